// Round 5
// baseline (462.819 us; speedup 1.0000x reference)
//
#include <hip/hip_runtime.h>
#include <math.h>

#define DIMC 512
#define VDIM 256
#define NVARS 320
#define NTOK 32768
#define NELEM (NTOK*DIMC)       // 16777216
#define IDX_OFF NELEM
#define PPL_OFF (NELEM + NTOK*2)
#define KM_OFF (PPL_OFF + 1)

// ws layout: doubles first: dsum[32] (double idx 0..32), dssq[32] (double idx 32..64)
//   == float offsets [0..128). Then float area:
#define OFF_MU   128   // 32 f32
#define OFF_RSTD 160   // 32 f32
#define OFF_LOSS 192   // 1 f32
#define OFF_ESQ  256   // 768 f32 -> [256,1024): v in [0,384), pad v>=320 = +inf
#define OFF_HIST 1024  // 640 i32 -> [1024,1664)
#define WS_ZERO_FLOATS 1664

// LDS tile [32 k][128 col]: phys scalar idx; XOR swizzle on f4-col by k&7.
// Staged b128 writes spread 8 lanes over all 8 4-bank groups; compute reads
// are broadcast (a) or 2-way (e/b) -> conflict-free.
__device__ __forceinline__ int tidx(int kl, int col) {
    return kl * 128 + (((((col) >> 2) ^ (kl & 7)) & 31) << 2) + (col & 3);
}

__global__ void k_init(float* ws) {
    int i = blockIdx.x * 256 + threadIdx.x;
    if (i < WS_ZERO_FLOATS) {
        // esq pad region [896,1024) = v in [320,384) -> +inf (never argmin-selected)
        ws[i] = (i >= OFF_ESQ + 640 && i < OFF_ESQ + 768) ? __builtin_inff() : 0.0f;
    }
}

// e_sq[v*2+g] = sum_d emb[v][g][d]^2, fp64 accumulate -> correctly-rounded f32
__global__ void k_esq(const float* __restrict__ emb, float* ws) {
    int wave = blockIdx.x * 4 + (threadIdx.x >> 6);
    int lane = threadIdx.x & 63;
    const float* p = emb + (size_t)wave * VDIM;
    double s = 0.0;
    for (int j = lane; j < VDIM; j += 64) { double v = (double)p[j]; s += v * v; }
    for (int off = 32; off; off >>= 1) s += __shfl_down(s, off);
    if (lane == 0) ws[OFF_ESQ + wave] = (float)s;
}

// y_t = (x @ W^T)^T per group: y_t[g*256+o][tok]. Tile 128 tok x 128 o,
// K in 32-chunks (8 stages, LDS 37KB -> ~4 blocks/CU). Fused GN stats (fp64).
__global__ __launch_bounds__(256, 2) void k_gemm(const float* __restrict__ x,
                                                 const float* __restrict__ w,
                                                 float* __restrict__ yt, float* ws) {
    __shared__ float As[32 * 128];   // [k][tok] swizzled
    __shared__ float Ws[32 * 128];   // [k][o]   swizzled
    __shared__ double red1[256];
    __shared__ double red2[256];
    const int tid = threadIdx.x;
    const int tx = tid & 15, ty = tid >> 4;
    const int rr = tid >> 1, th = tid & 1;   // staging: row 0..127, k-half
    const int tok0 = blockIdx.x * 128;
    const int o0 = blockIdx.y * 128;
    const int g = blockIdx.z;
    const int b = tok0 >> 11;

    float acc[8][8];
#pragma unroll
    for (int i = 0; i < 8; i++)
#pragma unroll
        for (int j = 0; j < 8; j++) acc[i][j] = 0.0f;

    for (int kc = 0; kc < 8; kc++) {
        __syncthreads();
        // stage As: thread owns tok-row rr, 16 k-floats (transpose scalar writes, 2-way)
#pragma unroll
        for (int it = 0; it < 4; it++) {
            const int kl = th * 16 + it * 4;
            float4 v = *(const float4*)(x + (size_t)(tok0 + rr) * DIMC + g * VDIM + kc * 32 + kl);
            As[tidx(kl + 0, rr)] = v.x; As[tidx(kl + 1, rr)] = v.y;
            As[tidx(kl + 2, rr)] = v.z; As[tidx(kl + 3, rr)] = v.w;
        }
        // stage Ws: thread owns o-row rr
#pragma unroll
        for (int it = 0; it < 4; it++) {
            const int kl = th * 16 + it * 4;
            float4 v = *(const float4*)(w + (size_t)(g * 256 + o0 + rr) * 256 + kc * 32 + kl);
            Ws[tidx(kl + 0, rr)] = v.x; Ws[tidx(kl + 1, rr)] = v.y;
            Ws[tidx(kl + 2, rr)] = v.z; Ws[tidx(kl + 3, rr)] = v.w;
        }
        __syncthreads();
        const float4* A4 = (const float4*)As;
        const float4* W4 = (const float4*)Ws;
#pragma unroll 4
        for (int k = 0; k < 32; k++) {
            const int s = k & 7;
            float4 a0 = A4[k * 32 + ((2 * ty) ^ s)];
            float4 a1 = A4[k * 32 + ((2 * ty + 1) ^ s)];
            float4 b0 = W4[k * 32 + (tx ^ s)];
            float4 b1 = W4[k * 32 + (16 + (tx ^ s))];
            float av[8] = {a0.x, a0.y, a0.z, a0.w, a1.x, a1.y, a1.z, a1.w};
            float bv[8] = {b0.x, b0.y, b0.z, b0.w, b1.x, b1.y, b1.z, b1.w};
#pragma unroll
            for (int i = 0; i < 8; i++)
#pragma unroll
                for (int j = 0; j < 8; j++) acc[i][j] = fmaf(av[i], bv[j], acc[i][j]);
        }
    }
    // epilogue: fp64 stats + transposed y_t stores
    double s1 = 0.0, s2 = 0.0;
#pragma unroll
    for (int i = 0; i < 8; i++)
#pragma unroll
        for (int j = 0; j < 8; j++) {
            s1 += (double)acc[i][j];
            s2 += (double)acc[i][j] * acc[i][j];
        }
#pragma unroll
    for (int j = 0; j < 8; j++) {
        const int o = o0 + ((j < 4) ? (tx * 4 + j) : (64 + tx * 4 + (j - 4)));
        float4 lo = make_float4(acc[0][j], acc[1][j], acc[2][j], acc[3][j]);
        float4 hi = make_float4(acc[4][j], acc[5][j], acc[6][j], acc[7][j]);
        float* p = yt + (size_t)(g * 256 + o) * NTOK + tok0 + ty * 8;
        *(float4*)p = lo;
        *(float4*)(p + 4) = hi;
    }
    red1[tid] = s1; red2[tid] = s2;
    __syncthreads();
    for (int s = 128; s; s >>= 1) {
        if (tid < s) { red1[tid] += red1[tid + s]; red2[tid] += red2[tid + s]; }
        __syncthreads();
    }
    if (tid == 0) {
        double* dws = (double*)ws;
        atomicAdd(&dws[b * 2 + g], red1[0]);
        atomicAdd(&dws[32 + b * 2 + g], red2[0]);
    }
}

__global__ void k_stats(float* ws) {
    int i = threadIdx.x;
    if (i < 32) {
        const double* d = (const double*)ws;
        double mu = d[i] * (1.0 / 524288.0);
        double var = d[32 + i] * (1.0 / 524288.0) - mu * mu;
        float varf = (float)var;
        ws[OFF_MU + i] = (float)mu;
        ws[OFF_RSTD + i] = 1.0f / sqrtf(varf + 1e-5f);
    }
}

// VQ: 3 v-tiles of 128 (320 padded to 384), K in 32-chunks, 8x8 micro.
// LDS 33KB -> ~4 blocks/CU. All numeric chains bit-identical to rounds 2-4:
// ze = fmaf((y-mu)*rstd, gw, gb); dot = k-serial FMA 0..255;
// zsq = fp64 serial-k; d2 = fl(fl(zsq - 2*dot) + esq); ties -> lowest v.
__global__ __launch_bounds__(256, 2) void k_vq(const float* __restrict__ emb,
                                               const float* __restrict__ gnw,
                                               const float* __restrict__ gnb,
                                               float* out, float* ws) {
    __shared__ float As[32 * 128];   // [k][tok] = ze, swizzled
    __shared__ float Es[32 * 128];   // [k][v], swizzled
    __shared__ float zsqs[128];
    __shared__ float lsum[16];

    const int tid = threadIdx.x;
    const int tx = tid & 15, ty = tid >> 4;
    const int ar = tid >> 3, aq = tid & 7;   // As staging: k-row 0..31, tok-octant
    const int vr = tid >> 1, vh = tid & 1;   // Es staging: v-row 0..127, k-half
    const int tok0 = blockIdx.x * 128;
    const int g = blockIdx.y;
    const int b = tok0 >> 11;
    const float mu = ws[OFF_MU + b * 2 + g];
    const float rstd = ws[OFF_RSTD + b * 2 + g];
    int* hist = ((int*)ws) + OFF_HIST;
    const float* yt = out;           // y_t[g*256+k][NTOK]

    float br[8]; int bvv[8];
    float zs[8];
#pragma unroll
    for (int i = 0; i < 8; i++) { br[i] = 3.0e38f; bvv[i] = 0; zs[i] = 0.0f; }
    double zacc = 0.0;

    for (int vt = 0; vt < 3; vt++) {
        float acc[8][8];
#pragma unroll
        for (int i = 0; i < 8; i++)
#pragma unroll
            for (int j = 0; j < 8; j++) acc[i][j] = 0.0f;

        for (int kc = 0; kc < 8; kc++) {
            __syncthreads();
            // ---- stage As: thread owns k-row ar; 4 b128 along tok, affine fused ----
            {
                const float sgw = gnw[g * VDIM + kc * 32 + ar];
                const float sgb = gnb[g * VDIM + kc * 32 + ar];
                const float* yrow = yt + (size_t)(g * 256 + kc * 32 + ar) * NTOK + tok0;
                const int s = ar & 7;
#pragma unroll
                for (int it = 0; it < 4; it++) {
                    const int t4 = it * 8 + aq;
                    float4 v = *(const float4*)(yrow + t4 * 4);
                    float4 z;
                    z.x = fmaf((v.x - mu) * rstd, sgw, sgb);
                    z.y = fmaf((v.y - mu) * rstd, sgw, sgb);
                    z.z = fmaf((v.z - mu) * rstd, sgw, sgb);
                    z.w = fmaf((v.w - mu) * rstd, sgw, sgb);
                    ((float4*)As)[ar * 32 + (t4 ^ s)] = z;
                }
            }
            // ---- stage Es: thread owns v-row vr; 16 k-floats transposed (pad -> 0) ----
            {
                const int vg = vt * 128 + vr;
                if (vg < NVARS) {
                    const float* erow = emb + (size_t)(vg * 2 + g) * VDIM + kc * 32;
#pragma unroll
                    for (int it = 0; it < 4; it++) {
                        const int kl = vh * 16 + it * 4;
                        float4 e = *(const float4*)(erow + kl);
                        Es[tidx(kl + 0, vr)] = e.x; Es[tidx(kl + 1, vr)] = e.y;
                        Es[tidx(kl + 2, vr)] = e.z; Es[tidx(kl + 3, vr)] = e.w;
                    }
                } else {
#pragma unroll
                    for (int it = 0; it < 4; it++) {
                        const int kl = vh * 16 + it * 4;
                        Es[tidx(kl + 0, vr)] = 0.0f; Es[tidx(kl + 1, vr)] = 0.0f;
                        Es[tidx(kl + 2, vr)] = 0.0f; Es[tidx(kl + 3, vr)] = 0.0f;
                    }
                }
            }
            __syncthreads();
            // ---- zsq pass (vt=0 only): tok = tid < 128, serial k order, fp64 ----
            if (vt == 0 && tid < 128) {
                for (int k = 0; k < 32; k++) {
                    float z = As[tidx(k, tid)];
                    zacc += (double)z * z;
                }
            }
            // ---- compute: 8 toks x 8 vs per thread ----
            const float4* A4 = (const float4*)As;
            const float4* E4 = (const float4*)Es;
#pragma unroll 4
            for (int k = 0; k < 32; k++) {
                const int s = k & 7;
                float4 a0 = A4[k * 32 + ((2 * ty) ^ s)];
                float4 a1 = A4[k * 32 + ((2 * ty + 1) ^ s)];
                float4 e0 = E4[k * 32 + (tx ^ s)];
                float4 e1 = E4[k * 32 + (16 + (tx ^ s))];
                float av[8] = {a0.x, a0.y, a0.z, a0.w, a1.x, a1.y, a1.z, a1.w};
                float ev[8] = {e0.x, e0.y, e0.z, e0.w, e1.x, e1.y, e1.z, e1.w};
#pragma unroll
                for (int i = 0; i < 8; i++)
#pragma unroll
                    for (int j = 0; j < 8; j++) acc[i][j] = fmaf(av[i], ev[j], acc[i][j]);
            }
        }
        if (vt == 0) {
            if (tid < 128) zsqs[tid] = (float)zacc;
            __syncthreads();
#pragma unroll
            for (int i = 0; i < 8; i++) zs[i] = zsqs[ty * 8 + i];
        }
        // fold argmin: d2 = fl(fl(zsq - 2*dot) + esq); strict < keeps lowest v
        float esql[8];
#pragma unroll
        for (int j = 0; j < 8; j++) {
            const int v = vt * 128 + ((j < 4) ? (tx * 4 + j) : (64 + tx * 4 + (j - 4)));
            esql[j] = ws[OFF_ESQ + (size_t)v * 2 + g];
        }
#pragma unroll
        for (int i = 0; i < 8; i++)
#pragma unroll
            for (int j = 0; j < 8; j++) {
                float t = zs[i] - 2.0f * acc[i][j];
                float d2 = t + esql[j];
                const int v = vt * 128 + ((j < 4) ? (tx * 4 + j) : (64 + tx * 4 + (j - 4)));
                if (d2 < br[i]) { br[i] = d2; bvv[i] = v; }
            }
    }
    // cross-thread (tx) lexicographic min, 16-wide shfl
#pragma unroll
    for (int i = 0; i < 8; i++) {
#pragma unroll
        for (int off = 8; off; off >>= 1) {
            float r2 = __shfl_down(br[i], off, 16);
            int v2 = __shfl_down(bvv[i], off, 16);
            if (r2 < br[i] || (r2 == br[i] && v2 < bvv[i])) { br[i] = r2; bvv[i] = v2; }
        }
    }
    float dlocal = 0.0f;
    if (tx == 0) {
#pragma unroll
        for (int i = 0; i < 8; i++) {
            const int tok = ty * 8 + i;
            out[IDX_OFF + (size_t)(tok0 + tok) * 2 + g] = (float)bvv[i];
            atomicAdd(&hist[g * 320 + bvv[i]], 1);
            dlocal += br[i];
        }
        lsum[ty] = dlocal;
    }
    __syncthreads();
    if (tid == 0) {
        float s = 0.0f;
        for (int t = 0; t < 16; t++) s += lsum[t];
        atomicAdd(&ws[OFF_LOSS], s);
    }
}

// x_out = zq gather: reads idx floats, overwrites the y_t region with zq.
// Kernel boundary = global barrier vs k_vq's y_t reads (y_t aliases x_out).
__global__ __launch_bounds__(256) void k_gather(const float* __restrict__ emb,
                                                float* out) {
    __shared__ int sidx[128];
    const int tid = threadIdx.x;
    const int tok0 = blockIdx.x * 64;
    if (tid < 128) sidx[tid] = (int)out[IDX_OFF + (size_t)tok0 * 2 + tid];
    __syncthreads();
#pragma unroll 4
    for (int it = 0; it < 32; it++) {
        const int j = it * 256 + tid;
        const int tl = j >> 7;           // token within block (0..63)
        const int c4 = j & 127;          // float4 index within row (0..127)
        const int g = c4 >> 6;
        const int v = sidx[tl * 2 + g];
        float4 e = *(const float4*)(emb + (size_t)(v * 2 + g) * VDIM + (c4 & 63) * 4);
        *(float4*)(out + (size_t)(tok0 + tl) * DIMC + c4 * 4) = e;
    }
}

__global__ void k_final(float* out, float* ws) {
    __shared__ float red[512];
    int tid = threadIdx.x;
    int* hist = ((int*)ws) + OFF_HIST;
    float ppl = 0.0f;
    for (int g = 0; g < 2; g++) {
        float term = 0.0f;
        if (tid < 320) {
            float p = (float)hist[g * 320 + tid] * (1.0f / 32768.0f);
            term = p * logf(p + 1e-7f);
        }
        red[tid] = term;
        __syncthreads();
        for (int s = 256; s; s >>= 1) {
            if (tid < s) red[tid] += red[tid + s];
            __syncthreads();
        }
        if (tid == 0) ppl += expf(-red[0]);
        __syncthreads();
    }
    if (tid == 0) {
        out[PPL_OFF] = ppl;
        out[KM_OFF] = 1.25f * ws[OFF_LOSS] / 16777216.0f;
    }
}

extern "C" void kernel_launch(void* const* d_in, const int* in_sizes, int n_in,
                              void* d_out, int out_size, void* d_ws, size_t ws_size,
                              hipStream_t stream) {
    (void)in_sizes; (void)n_in; (void)out_size; (void)ws_size;
    const float* x      = (const float*)d_in[0];
    const float* conv_w = (const float*)d_in[1];
    const float* gn_w   = (const float*)d_in[2];
    const float* gn_b   = (const float*)d_in[3];
    const float* emb    = (const float*)d_in[4];
    float* out = (float*)d_out;
    float* ws  = (float*)d_ws;

    hipLaunchKernelGGL(k_init,   dim3(7),         dim3(256), 0, stream, ws);
    hipLaunchKernelGGL(k_esq,    dim3(160),       dim3(256), 0, stream, emb, ws);
    hipLaunchKernelGGL(k_gemm,   dim3(256, 2, 2), dim3(256), 0, stream, x, conv_w, out, ws);
    hipLaunchKernelGGL(k_stats,  dim3(1),         dim3(64),  0, stream, ws);
    hipLaunchKernelGGL(k_vq,     dim3(256, 2),    dim3(256), 0, stream, emb, gn_w, gn_b, out, ws);
    hipLaunchKernelGGL(k_gather, dim3(512),       dim3(256), 0, stream, emb, out);
    hipLaunchKernelGGL(k_final,  dim3(1),         dim3(512), 0, stream, out, ws);
}